// Round 1
// baseline (784.278 us; speedup 1.0000x reference)
//
#include <hip/hip_runtime.h>
#include <hip/hip_bf16.h>

// Problem: B=4, H=16, S=1024, D=64, fp32.
// reference:
//   scores  = QK^T * scale                    [bh, s, t]
//   scores2 = scores @ mask^T                 [bh, s, u]  (contract t)
//   attn    = softmax(scores2, axis=-1)
//   context = attn @ V                        [bh, s, d]
// outputs: context (4*16*1024*64) then attn (4*16*1024*1024), concatenated.
//
// Reassociation: scores2 = scale * Q @ (mask @ K)^T  -> 4.5x fewer FLOPs.
//   M2[u,d] = sum_t mask[u,t] * K[t,d]   (stored transposed: M2T[d][u] in ws)

#define BH   64
#define S    1024
#define D    64
#define SCALE 0.125f

static __device__ __forceinline__ void fma4(float4& a, float s, const float4& b) {
    a.x = fmaf(s, b.x, a.x);
    a.y = fmaf(s, b.y, a.y);
    a.z = fmaf(s, b.z, a.z);
    a.w = fmaf(s, b.w, a.w);
}

// C = A @ B per batch-head.  A: [bh][1024][1024] row-major, B: [bh][1024][64].
// TRANS_OUT: store C transposed as [bh][64][1024] (for M2T), else [bh][1024][64].
template <bool TRANS_OUT>
__global__ __launch_bounds__(256) void gemm_ab(const float* __restrict__ A,
                                               const float* __restrict__ B,
                                               float* __restrict__ C) {
    const int bh  = blockIdx.y;
    const int u0  = blockIdx.x * 64;
    const int tid = threadIdx.x;
    const int tx  = tid & 15;   // -> 4 output cols (d)
    const int ty  = tid >> 4;   // -> 4 output rows (u)

    __shared__ float As[64][68];  // [u][t], pad 68: a-reads land 2-way (free)
    __shared__ float Bs[64][64];  // [t][d]

    const float* Ab = A + (size_t)bh * S * S;
    const float* Bb = B + (size_t)bh * S * D;

    float4 acc[4];  // acc[i] = C[u0+4*ty+i][4*tx .. +3]
#pragma unroll
    for (int i = 0; i < 4; i++) acc[i] = make_float4(0.f, 0.f, 0.f, 0.f);

    const int lr = tid >> 4;         // staging row 0..15 (+16k)
    const int lc = (tid & 15) * 4;   // staging col 0..60

    for (int t0 = 0; t0 < S; t0 += 64) {
#pragma unroll
        for (int k = 0; k < 4; k++) {
            float4 va = *(const float4*)&Ab[(size_t)(u0 + lr + 16 * k) * S + t0 + lc];
            *(float4*)&As[lr + 16 * k][lc] = va;
            float4 vb = *(const float4*)&Bb[(size_t)(t0 + lr + 16 * k) * D + lc];
            *(float4*)&Bs[lr + 16 * k][lc] = vb;
        }
        __syncthreads();
#pragma unroll
        for (int tt = 0; tt < 64; tt += 4) {
            float4 b0 = *(const float4*)&Bs[tt + 0][tx * 4];
            float4 b1 = *(const float4*)&Bs[tt + 1][tx * 4];
            float4 b2 = *(const float4*)&Bs[tt + 2][tx * 4];
            float4 b3 = *(const float4*)&Bs[tt + 3][tx * 4];
#pragma unroll
            for (int i = 0; i < 4; i++) {
                float4 a = *(const float4*)&As[ty * 4 + i][tt];
                fma4(acc[i], a.x, b0);
                fma4(acc[i], a.y, b1);
                fma4(acc[i], a.z, b2);
                fma4(acc[i], a.w, b3);
            }
        }
        __syncthreads();
    }

    if (TRANS_OUT) {
        float* Cb = C + (size_t)bh * D * S;  // [d][u]
#pragma unroll
        for (int i = 0; i < 4; i++) {
            const int u = u0 + ty * 4 + i;
            Cb[(size_t)(tx * 4 + 0) * S + u] = acc[i].x;
            Cb[(size_t)(tx * 4 + 1) * S + u] = acc[i].y;
            Cb[(size_t)(tx * 4 + 2) * S + u] = acc[i].z;
            Cb[(size_t)(tx * 4 + 3) * S + u] = acc[i].w;
        }
    } else {
        float* Cb = C + (size_t)bh * S * D;  // [u][d]
#pragma unroll
        for (int i = 0; i < 4; i++) {
            *(float4*)&Cb[(size_t)(u0 + ty * 4 + i) * D + tx * 4] = acc[i];
        }
    }
}

// logits[s,u] = scale * sum_d Q[s,d] * M2T[d][u]; row softmax; write attn.
// Block: 256 threads = 4 waves; wave w owns rows s0+4w .. s0+4w+3;
// lane l owns u in {c*256 + 4l + j : c in 0..3, j in 0..3}  (full 1024 per wave).
__global__ __launch_bounds__(256) void logits_softmax(const float* __restrict__ Q,
                                                      const float* __restrict__ M2T,
                                                      float* __restrict__ attn) {
    const int bh  = blockIdx.y;
    const int s0  = blockIdx.x * 16;
    const int tid = threadIdx.x;
    const int w   = tid >> 6;
    const int l   = tid & 63;

    __shared__ float Qs[16][68];
    {
        const int r = tid >> 4;
        const int c = (tid & 15) * 4;
        float4 v = *(const float4*)&Q[((size_t)bh * S + s0 + r) * D + c];
        // fold the 1/sqrt(d_k) scale into Q
        v.x *= SCALE; v.y *= SCALE; v.z *= SCALE; v.w *= SCALE;
        *(float4*)&Qs[r][c] = v;
    }
    __syncthreads();

    float4 acc[4][4];  // [r][c]
#pragma unroll
    for (int r = 0; r < 4; r++)
#pragma unroll
        for (int c = 0; c < 4; c++) acc[r][c] = make_float4(0.f, 0.f, 0.f, 0.f);

    const float* M2b = M2T + (size_t)bh * D * S;

#pragma unroll 4
    for (int d = 0; d < D; d++) {
        const float* row = M2b + (size_t)d * S;
        float4 m0 = *(const float4*)&row[0 * 256 + 4 * l];
        float4 m1 = *(const float4*)&row[1 * 256 + 4 * l];
        float4 m2 = *(const float4*)&row[2 * 256 + 4 * l];
        float4 m3 = *(const float4*)&row[3 * 256 + 4 * l];
        float q0 = Qs[w * 4 + 0][d];
        float q1 = Qs[w * 4 + 1][d];
        float q2 = Qs[w * 4 + 2][d];
        float q3 = Qs[w * 4 + 3][d];
        fma4(acc[0][0], q0, m0); fma4(acc[0][1], q0, m1); fma4(acc[0][2], q0, m2); fma4(acc[0][3], q0, m3);
        fma4(acc[1][0], q1, m0); fma4(acc[1][1], q1, m1); fma4(acc[1][2], q1, m2); fma4(acc[1][3], q1, m3);
        fma4(acc[2][0], q2, m0); fma4(acc[2][1], q2, m1); fma4(acc[2][2], q2, m2); fma4(acc[2][3], q2, m3);
        fma4(acc[3][0], q3, m0); fma4(acc[3][1], q3, m1); fma4(acc[3][2], q3, m2); fma4(acc[3][3], q3, m3);
    }

#pragma unroll
    for (int r = 0; r < 4; r++) {
        const int s = s0 + w * 4 + r;
        // row max
        float mx = -3.0e38f;
#pragma unroll
        for (int c = 0; c < 4; c++) {
            float4 v = acc[r][c];
            mx = fmaxf(mx, fmaxf(fmaxf(v.x, v.y), fmaxf(v.z, v.w)));
        }
#pragma unroll
        for (int off = 32; off >= 1; off >>= 1) mx = fmaxf(mx, __shfl_xor(mx, off));
        // exp + sum
        float sum = 0.f;
#pragma unroll
        for (int c = 0; c < 4; c++) {
            float4 v = acc[r][c];
            v.x = __expf(v.x - mx); v.y = __expf(v.y - mx);
            v.z = __expf(v.z - mx); v.w = __expf(v.w - mx);
            acc[r][c] = v;
            sum += v.x + v.y + v.z + v.w;
        }
#pragma unroll
        for (int off = 32; off >= 1; off >>= 1) sum += __shfl_xor(sum, off);
        const float inv = 1.0f / sum;
        float* out = attn + ((size_t)bh * S + s) * S;
#pragma unroll
        for (int c = 0; c < 4; c++) {
            float4 v = acc[r][c];
            v.x *= inv; v.y *= inv; v.z *= inv; v.w *= inv;
            *(float4*)&out[c * 256 + 4 * l] = v;
        }
    }
}

extern "C" void kernel_launch(void* const* d_in, const int* in_sizes, int n_in,
                              void* d_out, int out_size, void* d_ws, size_t ws_size,
                              hipStream_t stream) {
    const float* Q    = (const float*)d_in[0];
    const float* K    = (const float*)d_in[1];
    const float* V    = (const float*)d_in[2];
    const float* mask = (const float*)d_in[3];
    float* context = (float*)d_out;                              // [bh][1024][64]
    float* attn    = (float*)d_out + (size_t)BH * S * D;         // [bh][1024][1024]
    float* M2T     = (float*)d_ws;                               // [bh][64][1024] = 16.8 MB

    // 1) M2T = (mask @ K)^T per head
    gemm_ab<true><<<dim3(16, BH), 256, 0, stream>>>(mask, K, M2T);
    // 2) attn = softmax(scale * Q @ M2)
    logits_softmax<<<dim3(64, BH), 256, 0, stream>>>(Q, M2T, attn);
    // 3) context = attn @ V
    gemm_ab<false><<<dim3(16, BH), 256, 0, stream>>>(attn, V, context);
}